// Round 9
// baseline (459.439 us; speedup 1.0000x reference)
//
#include <hip/hip_runtime.h>
#include <hip/hip_fp16.h>
#include <math.h>

// Problem constants (from reference file)
constexpr int N_NODES  = 50000;
constexpr int N_EDGES  = 1600000;
constexpr int G_GRAPHS = 64;
constexpr int D        = 32;
constexpr int D_ATTR   = 16;
constexpr int N_RBF    = 8;

// rw(len) lookup table: 8192 intervals over [0, LMAX], nearest-neighbor, fp16.
constexpr int   TBL      = 8192;
constexpr int   TBL_ROWS = TBL + 1;
constexpr float LMAX     = 10.0f;

// Final per-node bucket layout (what conv consumes). deg ~ Poisson(32).
constexpr int BUCKET = 80;

// Phase-1 binning: dst-tiles of 64 nodes, 8 streams per tile.
// Stream count ~ Poisson(256), sigma ~ 16; CAPB = 384 = +8 sigma.
constexpr int NT     = 64;
constexpr int NTILES = (N_NODES + NT - 1) / NT;  // 782
constexpr int NGRP   = 8;
constexpr int CAPB   = 384;

typedef unsigned int uint4v __attribute__((ext_vector_type(4)));

__device__ __forceinline__ float silu(float x) {
    return x / (1.0f + __expf(-x));
}
__device__ __forceinline__ float h2f_lo(unsigned int w) {
    return __half2float(__ushort_as_half((unsigned short)(w & 0xFFFF)));
}
__device__ __forceinline__ float h2f_hi(unsigned int w) {
    return __half2float(__ushort_as_half((unsigned short)(w >> 16)));
}

// ---------------------------------------------------------------------------
// 1) Node init: x_attr = W_elem[x], h = x_attr@W0 + b0, hm0 = h@Wmsg[0] (fp16)
// ---------------------------------------------------------------------------
__global__ void node_init_kernel(const int* __restrict__ x,
                                 const float* __restrict__ W_elem,
                                 const float* __restrict__ W0,
                                 const float* __restrict__ b0,
                                 const float* __restrict__ Wmsg0,
                                 float* __restrict__ x_attr,
                                 float* __restrict__ h,
                                 __half* __restrict__ hm) {
    int t = blockIdx.x * blockDim.x + threadIdx.x;
    int n = t >> 5, c = t & 31;
    if (n >= N_NODES) return;
    int sp = x[n];
    const float* we = W_elem + sp * D_ATTR;
    float acc = b0[c];
#pragma unroll
    for (int a = 0; a < D_ATTR; ++a) acc += we[a] * W0[a * D + c];
    h[n * D + c] = acc;
    if (c < D_ATTR) x_attr[n * D_ATTR + c] = we[c];
    float m = 0.0f;
#pragma unroll
    for (int j = 0; j < D; ++j) {
        float hj = __shfl(acc, j, 32);
        m = fmaf(hj, Wmsg0[j * D + c], m);
    }
    hm[n * D + c] = __float2half(m);
}

// ---------------------------------------------------------------------------
// 2a) Phase 1: edge geometry -> append 16B record to per-(tile,grp) stream.
//     Streams are written sequentially by concurrent waves -> write-combined
//     (rounds 5-8 measured 104-123 MB of writes from random per-edge stores;
//     lines, not bytes, are what amplify).
//     bin rec = { src | (tbl_idx<<16), dstLocal, half2(sw0,sw1), half(sw2) }
// ---------------------------------------------------------------------------
__global__ void scatter_kernel(const int* __restrict__ eidx,
                               const float* __restrict__ pos,
                               const float* __restrict__ period,
                               const float* __restrict__ wsh,
                               int* __restrict__ bin_cursor,
                               uint4v* __restrict__ bins) {
    int e = blockIdx.x * blockDim.x + threadIdx.x;
    if (e >= N_EDGES) return;
    int s = eidx[e];
    int d = eidx[N_EDGES + e];
    float vx = pos[d * 3 + 0] - pos[s * 3 + 0] + period[e * 3 + 0];
    float vy = pos[d * 3 + 1] - pos[s * 3 + 1] + period[e * 3 + 1];
    float vz = pos[d * 3 + 2] - pos[s * 3 + 2] + period[e * 3 + 2];
    float len = sqrtf(vx * vx + vy * vy + vz * vz);
    float inv = 1.0f / (len + 1e-9f);
    int idx = (int)fminf(len * ((float)TBL / LMAX) + 0.5f, (float)TBL);
    float sw[3];
#pragma unroll
    for (int l = 0; l < 3; ++l)
        sw[l] = wsh[l * 4 + 0] + (vx * wsh[l * 4 + 1] + vy * wsh[l * 4 + 2] + vz * wsh[l * 4 + 3]) * inv;

    int tile = d >> 6;
    int dl = d & (NT - 1);
    int stream = tile * NGRP + (blockIdx.x & (NGRP - 1));
    int slot = atomicAdd(&bin_cursor[stream], 1);
    if (slot < CAPB) {
        unsigned u0 = (unsigned)__half_as_ushort(__float2half(sw[0]));
        unsigned u1 = (unsigned)__half_as_ushort(__float2half(sw[1]));
        unsigned u2 = (unsigned)__half_as_ushort(__float2half(sw[2]));
        uint4v r;
        r.x = (unsigned)s | ((unsigned)idx << 16);
        r.y = (unsigned)dl;
        r.z = u0 | (u1 << 16);
        r.w = u2;
        bins[(size_t)stream * CAPB + slot] = r;
    }
}

// ---------------------------------------------------------------------------
// 2b) Phase 2: block-per-tile shuffle. Read the tile's 8 bins coalescedly,
//     assign per-node slots via LDS cursors, write into the per-node bucket
//     layout. All of a tile's writes land in an 80 KB L2-resident window ->
//     write-combined (amp ~1.2x vs 4-6x for global random scatter).
//     final rec = { src | (tbl_idx<<16), half2(sw0,sw1), half(sw2), 0 }
// ---------------------------------------------------------------------------
__global__ __launch_bounds__(256) void shuffle_kernel(const uint4v* __restrict__ bins,
                                                      const int* __restrict__ bin_cursor,
                                                      uint4v* __restrict__ rec,
                                                      int* __restrict__ count) {
    __shared__ int lcur[NT];
    int tile = blockIdx.x;
    int tid = threadIdx.x;
    if (tid < NT) lcur[tid] = 0;
    __syncthreads();

    for (int grp = 0; grp < NGRP; ++grp) {
        int stream = tile * NGRP + grp;
        int cnt = bin_cursor[stream];
        if (cnt > CAPB) cnt = CAPB;
        const uint4v* base = bins + (size_t)stream * CAPB;
        for (int i = tid; i < cnt; i += 256) {
            uint4v r = __builtin_nontemporal_load(base + i);
            int dl = (int)r.y;
            int slot = atomicAdd(&lcur[dl], 1);
            if (slot < BUCKET) {
                uint4v o;
                o.x = r.x; o.y = r.z; o.z = r.w; o.w = 0u;
                rec[(size_t)(tile * NT + dl) * BUCKET + slot] = o;
            }
        }
    }
    __syncthreads();
    if (tid < NT) {
        int node = tile * NT + tid;
        if (node < N_NODES) {
            int cnt = lcur[tid];
            count[node] = cnt < BUCKET ? cnt : BUCKET;
        }
    }
}

// ---------------------------------------------------------------------------
// 3) Build fp16 rw(len) tables for the 3 layers: table[l][idx][c]
// ---------------------------------------------------------------------------
__global__ void table_kernel(const float* __restrict__ Wr1,
                             const float* __restrict__ br1,
                             const float* __restrict__ Wr2,
                             __half* __restrict__ table) {
    int t = blockIdx.x * blockDim.x + threadIdx.x;
    if (t >= 3 * TBL_ROWS) return;
    int l = t / TBL_ROWS;
    int idx = t % TBL_ROWS;
    float len = (float)idx * (LMAX / (float)TBL);
    const float gamma = (8.0f / 5.0f) * (8.0f / 5.0f);  // (N_RBF/CUTOFF)^2
    float rbf[N_RBF];
#pragma unroll
    for (int k = 0; k < N_RBF; ++k) {
        float dd = len - (float)k * (5.0f / 7.0f);  // linspace(0, CUTOFF, 8)
        rbf[k] = __expf(-gamma * dd * dd);
    }
    float out[D];
#pragma unroll
    for (int c = 0; c < D; ++c) out[c] = 0.0f;
    for (int j = 0; j < D; ++j) {
        float z = br1[l * D + j];
#pragma unroll
        for (int k = 0; k < N_RBF; ++k) z += rbf[k] * Wr1[l * N_RBF * D + k * D + j];
        z = fmaxf(z, 0.0f);
        const float* w2 = Wr2 + l * D * D + j * D;
#pragma unroll
        for (int c = 0; c < D; ++c) out[c] += z * w2[c];
    }
    __half* dst = table + ((size_t)(l * TBL_ROWS + idx)) * D;
#pragma unroll
    for (int c = 0; c < D; ++c) dst[c] = __float2half(out[c]);
}

// ---------------------------------------------------------------------------
// 4) Conv layer: wave-per-node, quarter-wave per edge slot, half2 channel
//    pairs (round-7 structure — best measured). rec loads are NONTEMPORAL:
//    the 25.6 MB/conv stream must not evict hm (3.2 MB) + table (0.5 MB)
//    from per-XCD L2 — keeping those resident turns the per-edge gathers
//    into L2 hits. Batch-8 rec prefetch = 32 records in flight per wave.
// ---------------------------------------------------------------------------
template <int LAYER, bool WRITE_HM>
__global__ void conv_kernel(const __half* __restrict__ hm,
                            const uint4v* __restrict__ rec,
                            const int* __restrict__ count,
                            const float* __restrict__ x_attr,
                            const __half* __restrict__ table,
                            const float* __restrict__ Wattr,
                            const float* __restrict__ Wself,
                            const float* __restrict__ bconv,
                            const float* __restrict__ Wmsg_next,
                            float* __restrict__ h,
                            __half* __restrict__ hm_next) {
    int gtid = blockIdx.x * blockDim.x + threadIdx.x;
    int node = gtid >> 6;
    if (node >= N_NODES) return;
    int lane = threadIdx.x & 63;
    int qw = lane >> 4;   // quarter id 0..3
    int q  = lane & 15;   // channel-pair id: channels {2q, 2q+1}

    const __half2* tab2 = (const __half2*)(table + ((size_t)LAYER * TBL_ROWS) * D);
    const __half2* hm2  = (const __half2*)hm;
    int cnt = count[node];
    int beg = node * BUCKET;

    float ax = 0.0f, ay = 0.0f;
    if (cnt > 0) {
        int end = beg + cnt;
        int last = end - 1;
        for (int base = beg + qw; base < end; base += 32) {
            uint4v r[8];
#pragma unroll
            for (int j = 0; j < 8; ++j) {
                int slot = base + 4 * j;
                r[j] = __builtin_nontemporal_load(rec + (slot <= last ? slot : last));
            }
#pragma unroll
            for (int j = 0; j < 8; ++j) {
                int slot = base + 4 * j;
                int s = (int)(r[j].x & 0xFFFFu);
                int i = (int)(r[j].x >> 16);
                float sw = (LAYER == 0) ? h2f_lo(r[j].y)
                         : (LAYER == 1) ? h2f_hi(r[j].y)
                                        : h2f_lo(r[j].z);
                sw = (slot <= last) ? sw : 0.0f;  // kill clamped duplicates
                float2 tf = __half22float2(tab2[i * 16 + q]);
                float2 mf = __half22float2(hm2[s * 16 + q]);
                ax = fmaf(tf.x * mf.x, sw, ax);
                ay = fmaf(tf.y * mf.y, sw, ay);
            }
        }
    }
    // reduce across the 4 quarters (lanes q, q+16, q+32, q+48)
    ax += __shfl_xor(ax, 16);
    ax += __shfl_xor(ax, 32);
    ay += __shfl_xor(ay, 16);
    ay += __shfl_xor(ay, 32);

    // redistribute to 32-lane channel layout: lane c needs pair c>>1, elem c&1
    int c = lane & 31;
    float vx = __shfl(ax, c >> 1);
    float vy = __shfl(ay, c >> 1);
    float agg = (c & 1) ? vy : vx;

    if ((lane >> 5) == 0) {
        float hload = h[node * D + c];
        float xload = (c < D_ATTR) ? x_attr[node * D_ATTR + c] : 0.0f;
        float pre = agg + bconv[LAYER * D + c];
        const float* Ws = Wself + LAYER * D * D;
        const float* Wa = Wattr + LAYER * D_ATTR * D;
#pragma unroll
        for (int j = 0; j < D; ++j) pre = fmaf(__shfl(hload, j), Ws[j * D + c], pre);
#pragma unroll
        for (int j = 0; j < D_ATTR; ++j) pre = fmaf(__shfl(xload, j), Wa[j * D + c], pre);
        float hn = silu(pre);
        h[node * D + c] = hn;
        if (WRITE_HM) {
            float m = 0.0f;
#pragma unroll
            for (int j = 0; j < D; ++j) m = fmaf(__shfl(hn, j), Wmsg_next[j * D + c], m);
            hm_next[node * D + c] = __float2half(m);
        }
    }
}

// ---------------------------------------------------------------------------
// 5) Readout: per-node MLP scalar, wave-aggregated segment-sum (batch sorted
//    -> nearly all waves uniform: ~1 atomic per wave).
// ---------------------------------------------------------------------------
__global__ void readout_kernel(const float* __restrict__ h,
                               const int* __restrict__ batch,
                               const float* __restrict__ Wp1,
                               const float* __restrict__ bp1,
                               const float* __restrict__ Wp2,
                               const float* __restrict__ bp2,
                               float* __restrict__ out) {
    int n = blockIdx.x * blockDim.x + threadIdx.x;
    float s = 0.0f;
    int b = -1;
    if (n < N_NODES) {
        b = batch[n];
        const float* hrow = h + n * D;
        float acc2 = bp2[0];
#pragma unroll
        for (int m = 0; m < 16; ++m) {
            float a = bp1[m];
#pragma unroll
            for (int j = 0; j < D; ++j) a += hrow[j] * Wp1[j * 16 + m];
            acc2 += silu(a) * Wp2[m];
        }
        s = acc2;  // SCALE=1, SHIFT=0 baked in
    }
    unsigned long long valid = __ballot(n < N_NODES);
    if (valid == 0ull) return;
    int firstLane = __ffsll(valid) - 1;
    int b0v = __shfl(b, firstLane);
    bool ok = (b == b0v) || (n >= N_NODES);
    if (__all(ok)) {
#pragma unroll
        for (int o = 32; o > 0; o >>= 1) s += __shfl_down(s, o);
        if ((threadIdx.x & 63) == 0) atomicAdd(out + b0v, s);
    } else {
        if (n < N_NODES) atomicAdd(out + b, s);
    }
}

// ---------------------------------------------------------------------------
extern "C" void kernel_launch(void* const* d_in, const int* in_sizes, int n_in,
                              void* d_out, int out_size, void* d_ws, size_t ws_size,
                              hipStream_t stream) {
    const int*   x      = (const int*)d_in[0];
    const float* pos    = (const float*)d_in[1];
    const int*   eidx   = (const int*)d_in[2];
    const float* period = (const float*)d_in[3];
    const int*   batch  = (const int*)d_in[4];
    const float* W_elem = (const float*)d_in[5];
    const float* W0     = (const float*)d_in[6];
    const float* b0     = (const float*)d_in[7];
    const float* Wr1    = (const float*)d_in[8];
    const float* br1    = (const float*)d_in[9];
    const float* Wr2    = (const float*)d_in[10];
    const float* Wmsg   = (const float*)d_in[11];
    const float* Wattr  = (const float*)d_in[12];
    const float* Wself  = (const float*)d_in[13];
    const float* bconv  = (const float*)d_in[14];
    const float* wsh    = (const float*)d_in[15];
    const float* Wp1    = (const float*)d_in[16];
    const float* bp1    = (const float*)d_in[17];
    const float* Wp2    = (const float*)d_in[18];
    const float* bp2    = (const float*)d_in[19];

    char* base = (char*)d_ws;
    size_t off = 0;
    auto carve = [&](size_t bytes) -> void* {
        void* p = base + off;
        off = (off + bytes + 255) & ~(size_t)255;
        return p;
    };
    float*  x_attr     = (float*)carve((size_t)N_NODES * D_ATTR * 4);
    float*  h          = (float*)carve((size_t)N_NODES * D * 4);
    __half* hm_a       = (__half*)carve((size_t)N_NODES * D * 2);
    __half* hm_b       = (__half*)carve((size_t)N_NODES * D * 2);
    uint4v* rec        = (uint4v*)carve((size_t)NTILES * NT * BUCKET * 16);
    uint4v* bins       = (uint4v*)carve((size_t)NTILES * NGRP * CAPB * 16);
    int*    bin_cursor = (int*)carve((size_t)NTILES * NGRP * 4);
    int*    count      = (int*)carve((size_t)NTILES * NT * 4);
    __half* table      = (__half*)carve((size_t)3 * TBL_ROWS * D * 2);
    (void)ws_size; (void)in_sizes; (void)n_in; (void)out_size;

    hipMemsetAsync(bin_cursor, 0, (size_t)NTILES * NGRP * 4, stream);
    hipMemsetAsync(d_out, 0, (size_t)G_GRAPHS * 4, stream);

    node_init_kernel<<<(N_NODES * 32 + 255) / 256, 256, 0, stream>>>(
        x, W_elem, W0, b0, Wmsg + 0 * D * D, x_attr, h, hm_a);
    scatter_kernel<<<(N_EDGES + 255) / 256, 256, 0, stream>>>(eidx, pos, period, wsh,
                                                              bin_cursor, bins);
    table_kernel<<<(3 * TBL_ROWS + 127) / 128, 128, 0, stream>>>(Wr1, br1, Wr2, table);
    shuffle_kernel<<<NTILES, 256, 0, stream>>>(bins, bin_cursor, rec, count);

    int cgrid = (N_NODES * 64 + 255) / 256;
    conv_kernel<0, true><<<cgrid, 256, 0, stream>>>(
        hm_a, rec, count, x_attr, table, Wattr, Wself, bconv, Wmsg + 1 * D * D, h, hm_b);
    conv_kernel<1, true><<<cgrid, 256, 0, stream>>>(
        hm_b, rec, count, x_attr, table, Wattr, Wself, bconv, Wmsg + 2 * D * D, h, hm_a);
    conv_kernel<2, false><<<cgrid, 256, 0, stream>>>(
        hm_a, rec, count, x_attr, table, Wattr, Wself, bconv, nullptr, h, nullptr);

    readout_kernel<<<(N_NODES + 255) / 256, 256, 0, stream>>>(h, batch, Wp1, bp1, Wp2, bp2,
                                                              (float*)d_out);
}

// Round 10
// 423.344 us; speedup vs baseline: 1.0853x; 1.0853x over previous
//
#include <hip/hip_runtime.h>
#include <hip/hip_fp16.h>
#include <math.h>

// Problem constants (from reference file)
constexpr int N_NODES  = 50000;
constexpr int N_EDGES  = 1600000;
constexpr int G_GRAPHS = 64;
constexpr int D        = 32;
constexpr int D_ATTR   = 16;
constexpr int N_RBF    = 8;

// rw(len) lookup table: 8192 intervals over [0, LMAX], nearest-neighbor, fp16.
constexpr int   TBL      = 8192;
constexpr int   TBL_ROWS = TBL + 1;
constexpr float LMAX     = 10.0f;

// Final per-node bucket layout (what conv consumes). deg ~ Poisson(32).
constexpr int BUCKET = 80;

// dst-tiles of 64 nodes; per-tile contiguous streams filled by counting sort.
constexpr int NT     = 64;
constexpr int NTILES = (N_NODES + NT - 1) / NT;  // 782
// Tile edge count ~ Poisson(2048), sigma ~45; +8.5 sigma.
constexpr int TCAP   = 2432;
// Phase-1 chunking: 256 threads x 32 edges = 8192 edges per block.
constexpr int EPB    = 8192;
constexpr int NBLK1  = (N_EDGES + EPB - 1) / EPB;  // 196

typedef unsigned int uint4v __attribute__((ext_vector_type(4)));

__device__ __forceinline__ float silu(float x) {
    return x / (1.0f + __expf(-x));
}
__device__ __forceinline__ float h2f_lo(unsigned int w) {
    return __half2float(__ushort_as_half((unsigned short)(w & 0xFFFF)));
}
__device__ __forceinline__ float h2f_hi(unsigned int w) {
    return __half2float(__ushort_as_half((unsigned short)(w >> 16)));
}

// ---------------------------------------------------------------------------
// 1) Node init. Computes h0 in registers, then (shared-shfl):
//      hm0 = h0@Wmsg[0]              (fp16)
//      hs0 = h0@Wself[0] + x_attr@Wattr[0] + bconv[0]   (fp32)
//      xa1 = x_attr@Wattr[1] + bconv[1],  xa2 = ... [2] (fp32)
//    h and x_attr are never materialized (conv<0/1> don't need them).
// ---------------------------------------------------------------------------
__global__ void node_init_kernel(const int* __restrict__ x,
                                 const float* __restrict__ W_elem,
                                 const float* __restrict__ W0,
                                 const float* __restrict__ b0,
                                 const float* __restrict__ Wmsg0,
                                 const float* __restrict__ Wself0,
                                 const float* __restrict__ Wattr,
                                 const float* __restrict__ bconv,
                                 __half* __restrict__ hm0,
                                 float* __restrict__ hs0,
                                 float* __restrict__ xa1,
                                 float* __restrict__ xa2) {
    int t = blockIdx.x * blockDim.x + threadIdx.x;
    int n = t >> 5, c = t & 31;
    if (n >= N_NODES) return;
    int sp = x[n];
    const float* we = W_elem + sp * D_ATTR;
    float xv = (c < D_ATTR) ? we[c] : 0.0f;  // x_attr element for lane c<16
    float acc = b0[c];
#pragma unroll
    for (int a = 0; a < D_ATTR; ++a) acc += we[a] * W0[a * D + c];
    // shared-shfl double GEMM on h0
    float m = 0.0f, s = 0.0f;
#pragma unroll
    for (int j = 0; j < D; ++j) {
        float hj = __shfl(acc, j, 32);
        m = fmaf(hj, Wmsg0[j * D + c], m);
        s = fmaf(hj, Wself0[j * D + c], s);
    }
    // x_attr @ Wattr[l] for l=0,1,2 (shared shfl)
    float a0 = bconv[0 * D + c], a1 = bconv[1 * D + c], a2 = bconv[2 * D + c];
#pragma unroll
    for (int j = 0; j < D_ATTR; ++j) {
        float xj = __shfl(xv, j, 32);
        a0 = fmaf(xj, Wattr[0 * D_ATTR * D + j * D + c], a0);
        a1 = fmaf(xj, Wattr[1 * D_ATTR * D + j * D + c], a1);
        a2 = fmaf(xj, Wattr[2 * D_ATTR * D + j * D + c], a2);
    }
    hm0[n * D + c] = __float2half(m);
    hs0[n * D + c] = s + a0;
    xa1[n * D + c] = a1;
    xa2[n * D + c] = a2;
}

// ---------------------------------------------------------------------------
// 2a) Phase 1: block-chunked counting sort into per-TILE contiguous streams.
//     Each block: LDS histogram over 782 tiles -> ONE global atomicAdd per
//     (block,tile) reserves a contiguous range -> LDS-ranked writes. Edges of
//     one tile within a block (~10.5 avg) land on ~3 consecutive lines
//     written in one burst by one block -> write-combined (rounds 5-9: slot
//     interleaving across blocks defeated combining; amp 3-4x).
//     bin rec = { src | (tbl_idx<<16), dstLocal, half2(sw0,sw1), half(sw2) }
// ---------------------------------------------------------------------------
__global__ __launch_bounds__(256) void scatter_kernel(const int* __restrict__ eidx,
                                                      const float* __restrict__ pos,
                                                      const float* __restrict__ period,
                                                      const float* __restrict__ wsh,
                                                      int* __restrict__ tile_cursor,
                                                      uint4v* __restrict__ bins) {
    __shared__ int hist[NTILES];
    __shared__ int basev[NTILES];
    int tid = threadIdx.x;
    int e0 = blockIdx.x * EPB;
    for (int i = tid; i < NTILES; i += 256) hist[i] = 0;
    __syncthreads();
    // pass A: histogram (dst only; cheap coalesced load)
#pragma unroll 4
    for (int i = 0; i < EPB / 256; ++i) {
        int e = e0 + tid + 256 * i;
        if (e < N_EDGES) atomicAdd(&hist[eidx[N_EDGES + e] >> 6], 1);
    }
    __syncthreads();
    // pass B: reserve global ranges, reset hist for ranking
    for (int t = tid; t < NTILES; t += 256) {
        int cnt = hist[t];
        basev[t] = (cnt > 0) ? atomicAdd(&tile_cursor[t], cnt) : 0;
        hist[t] = 0;
    }
    __syncthreads();
    // pass C: full geometry + ranked write
    for (int i = 0; i < EPB / 256; ++i) {
        int e = e0 + tid + 256 * i;
        if (e >= N_EDGES) continue;
        int s = eidx[e];
        int d = eidx[N_EDGES + e];
        float vx = pos[d * 3 + 0] - pos[s * 3 + 0] + period[e * 3 + 0];
        float vy = pos[d * 3 + 1] - pos[s * 3 + 1] + period[e * 3 + 1];
        float vz = pos[d * 3 + 2] - pos[s * 3 + 2] + period[e * 3 + 2];
        float len = sqrtf(vx * vx + vy * vy + vz * vz);
        float inv = 1.0f / (len + 1e-9f);
        int idx = (int)fminf(len * ((float)TBL / LMAX) + 0.5f, (float)TBL);
        float sw[3];
#pragma unroll
        for (int l = 0; l < 3; ++l)
            sw[l] = wsh[l * 4 + 0] + (vx * wsh[l * 4 + 1] + vy * wsh[l * 4 + 2] + vz * wsh[l * 4 + 3]) * inv;
        int tile = d >> 6;
        int rank = atomicAdd(&hist[tile], 1);
        int slot = basev[tile] + rank;
        if (slot < TCAP) {
            unsigned u0 = (unsigned)__half_as_ushort(__float2half(sw[0]));
            unsigned u1 = (unsigned)__half_as_ushort(__float2half(sw[1]));
            unsigned u2 = (unsigned)__half_as_ushort(__float2half(sw[2]));
            uint4v r;
            r.x = (unsigned)s | ((unsigned)idx << 16);
            r.y = (unsigned)(d & (NT - 1));
            r.z = u0 | (u1 << 16);
            r.w = u2;
            bins[(size_t)tile * TCAP + slot] = r;
        }
    }
}

// ---------------------------------------------------------------------------
// 2b) Phase 2: block-per-tile. Read the tile's stream coalescedly, assign
//     per-node slots via LDS cursors, write per-node bucket layout (all
//     writes land in an 80 KB L2-resident window -> combined).
//     final rec = { src | (tbl_idx<<16), half2(sw0,sw1), half(sw2), 0 }
// ---------------------------------------------------------------------------
__global__ __launch_bounds__(256) void shuffle_kernel(const uint4v* __restrict__ bins,
                                                      const int* __restrict__ tile_cursor,
                                                      uint4v* __restrict__ rec,
                                                      int* __restrict__ count) {
    __shared__ int lcur[NT];
    int tile = blockIdx.x;
    int tid = threadIdx.x;
    if (tid < NT) lcur[tid] = 0;
    __syncthreads();
    int cnt = tile_cursor[tile];
    if (cnt > TCAP) cnt = TCAP;
    const uint4v* base = bins + (size_t)tile * TCAP;
    for (int i = tid; i < cnt; i += 256) {
        uint4v r = __builtin_nontemporal_load(base + i);
        int dl = (int)r.y;
        int slot = atomicAdd(&lcur[dl], 1);
        if (slot < BUCKET) {
            uint4v o;
            o.x = r.x; o.y = r.z; o.z = r.w; o.w = 0u;
            rec[(size_t)(tile * NT + dl) * BUCKET + slot] = o;
        }
    }
    __syncthreads();
    if (tid < NT) {
        int node = tile * NT + tid;
        if (node < N_NODES) {
            int c = lcur[tid];
            count[node] = c < BUCKET ? c : BUCKET;
        }
    }
}

// ---------------------------------------------------------------------------
// 3) Build fp16 rw(len) tables for the 3 layers: table[l][idx][c]
// ---------------------------------------------------------------------------
__global__ void table_kernel(const float* __restrict__ Wr1,
                             const float* __restrict__ br1,
                             const float* __restrict__ Wr2,
                             __half* __restrict__ table) {
    int t = blockIdx.x * blockDim.x + threadIdx.x;
    if (t >= 3 * TBL_ROWS) return;
    int l = t / TBL_ROWS;
    int idx = t % TBL_ROWS;
    float len = (float)idx * (LMAX / (float)TBL);
    const float gamma = (8.0f / 5.0f) * (8.0f / 5.0f);  // (N_RBF/CUTOFF)^2
    float rbf[N_RBF];
#pragma unroll
    for (int k = 0; k < N_RBF; ++k) {
        float dd = len - (float)k * (5.0f / 7.0f);  // linspace(0, CUTOFF, 8)
        rbf[k] = __expf(-gamma * dd * dd);
    }
    float out[D];
#pragma unroll
    for (int c = 0; c < D; ++c) out[c] = 0.0f;
    for (int j = 0; j < D; ++j) {
        float z = br1[l * D + j];
#pragma unroll
        for (int k = 0; k < N_RBF; ++k) z += rbf[k] * Wr1[l * N_RBF * D + k * D + j];
        z = fmaxf(z, 0.0f);
        const float* w2 = Wr2 + l * D * D + j * D;
#pragma unroll
        for (int c = 0; c < D; ++c) out[c] += z * w2[c];
    }
    __half* dst = table + ((size_t)(l * TBL_ROWS + idx)) * D;
#pragma unroll
    for (int c = 0; c < D; ++c) dst[c] = __float2half(out[c]);
}

// ---------------------------------------------------------------------------
// 4) Conv layer: wave-per-node, quarter-wave per edge, half2 channel pairs
//    (round-7 edge loop — best measured). Lean epilogue:
//      hn = silu(agg + hs_in[n][c])            (hs carries self+attr+bias)
//      if NEXT: shared-shfl double GEMM -> hm_out (fp16), hs_out = s + xa_next
//      else   : h_final = hn
// ---------------------------------------------------------------------------
template <int LAYER, bool NEXT>
__global__ void conv_kernel(const __half* __restrict__ hm,
                            const float* __restrict__ hs,
                            const uint4v* __restrict__ rec,
                            const int* __restrict__ count,
                            const __half* __restrict__ table,
                            const float* __restrict__ Wmsg_next,
                            const float* __restrict__ Wself_next,
                            const float* __restrict__ xa_next,
                            __half* __restrict__ hm_out,
                            float* __restrict__ hs_out,
                            float* __restrict__ h_final) {
    int gtid = blockIdx.x * blockDim.x + threadIdx.x;
    int node = gtid >> 6;
    if (node >= N_NODES) return;
    int lane = threadIdx.x & 63;
    int qw = lane >> 4;   // quarter id 0..3
    int q  = lane & 15;   // channel-pair id: channels {2q, 2q+1}

    const __half2* tab2 = (const __half2*)(table + ((size_t)LAYER * TBL_ROWS) * D);
    const __half2* hm2  = (const __half2*)hm;
    int cnt = count[node];
    int beg = node * BUCKET;

    float ax = 0.0f, ay = 0.0f;
    if (cnt > 0) {
        int end = beg + cnt;
        int last = end - 1;
        for (int base = beg + qw; base < end; base += 32) {
            uint4v r[8];
#pragma unroll
            for (int j = 0; j < 8; ++j) {
                int slot = base + 4 * j;
                r[j] = __builtin_nontemporal_load(rec + (slot <= last ? slot : last));
            }
#pragma unroll
            for (int j = 0; j < 8; ++j) {
                int slot = base + 4 * j;
                int s = (int)(r[j].x & 0xFFFFu);
                int i = (int)(r[j].x >> 16);
                float sw = (LAYER == 0) ? h2f_lo(r[j].y)
                         : (LAYER == 1) ? h2f_hi(r[j].y)
                                        : h2f_lo(r[j].z);
                sw = (slot <= last) ? sw : 0.0f;  // kill clamped duplicates
                float2 tf = __half22float2(tab2[i * 16 + q]);
                float2 mf = __half22float2(hm2[s * 16 + q]);
                ax = fmaf(tf.x * mf.x, sw, ax);
                ay = fmaf(tf.y * mf.y, sw, ay);
            }
        }
    }
    // reduce across the 4 quarters (lanes q, q+16, q+32, q+48)
    ax += __shfl_xor(ax, 16);
    ax += __shfl_xor(ax, 32);
    ay += __shfl_xor(ay, 16);
    ay += __shfl_xor(ay, 32);

    // redistribute to 32-lane channel layout: lane c needs pair c>>1, elem c&1
    int c = lane & 31;
    float vx = __shfl(ax, c >> 1);
    float vy = __shfl(ay, c >> 1);
    float agg = (c & 1) ? vy : vx;

    if ((lane >> 5) == 0) {
        float hn = silu(agg + hs[node * D + c]);
        if (NEXT) {
            float m = 0.0f, s2 = 0.0f;
#pragma unroll
            for (int j = 0; j < D; ++j) {
                float hj = __shfl(hn, j);
                m  = fmaf(hj, Wmsg_next[j * D + c], m);
                s2 = fmaf(hj, Wself_next[j * D + c], s2);
            }
            hm_out[node * D + c] = __float2half(m);
            hs_out[node * D + c] = s2 + xa_next[node * D + c];
        } else {
            h_final[node * D + c] = hn;
        }
    }
}

// ---------------------------------------------------------------------------
// 5) Readout: per-node MLP scalar, wave-aggregated segment-sum (batch sorted
//    -> nearly all waves uniform: ~1 atomic per wave).
// ---------------------------------------------------------------------------
__global__ void readout_kernel(const float* __restrict__ h,
                               const int* __restrict__ batch,
                               const float* __restrict__ Wp1,
                               const float* __restrict__ bp1,
                               const float* __restrict__ Wp2,
                               const float* __restrict__ bp2,
                               float* __restrict__ out) {
    int n = blockIdx.x * blockDim.x + threadIdx.x;
    float s = 0.0f;
    int b = -1;
    if (n < N_NODES) {
        b = batch[n];
        const float* hrow = h + n * D;
        float acc2 = bp2[0];
#pragma unroll
        for (int m = 0; m < 16; ++m) {
            float a = bp1[m];
#pragma unroll
            for (int j = 0; j < D; ++j) a += hrow[j] * Wp1[j * 16 + m];
            acc2 += silu(a) * Wp2[m];
        }
        s = acc2;  // SCALE=1, SHIFT=0 baked in
    }
    unsigned long long valid = __ballot(n < N_NODES);
    if (valid == 0ull) return;
    int firstLane = __ffsll(valid) - 1;
    int b0v = __shfl(b, firstLane);
    bool ok = (b == b0v) || (n >= N_NODES);
    if (__all(ok)) {
#pragma unroll
        for (int o = 32; o > 0; o >>= 1) s += __shfl_down(s, o);
        if ((threadIdx.x & 63) == 0) atomicAdd(out + b0v, s);
    } else {
        if (n < N_NODES) atomicAdd(out + b, s);
    }
}

// ---------------------------------------------------------------------------
extern "C" void kernel_launch(void* const* d_in, const int* in_sizes, int n_in,
                              void* d_out, int out_size, void* d_ws, size_t ws_size,
                              hipStream_t stream) {
    const int*   x      = (const int*)d_in[0];
    const float* pos    = (const float*)d_in[1];
    const int*   eidx   = (const int*)d_in[2];
    const float* period = (const float*)d_in[3];
    const int*   batch  = (const int*)d_in[4];
    const float* W_elem = (const float*)d_in[5];
    const float* W0     = (const float*)d_in[6];
    const float* b0     = (const float*)d_in[7];
    const float* Wr1    = (const float*)d_in[8];
    const float* br1    = (const float*)d_in[9];
    const float* Wr2    = (const float*)d_in[10];
    const float* Wmsg   = (const float*)d_in[11];
    const float* Wattr  = (const float*)d_in[12];
    const float* Wself  = (const float*)d_in[13];
    const float* bconv  = (const float*)d_in[14];
    const float* wsh    = (const float*)d_in[15];
    const float* Wp1    = (const float*)d_in[16];
    const float* bp1    = (const float*)d_in[17];
    const float* Wp2    = (const float*)d_in[18];
    const float* bp2    = (const float*)d_in[19];

    char* base = (char*)d_ws;
    size_t off = 0;
    auto carve = [&](size_t bytes) -> void* {
        void* p = base + off;
        off = (off + bytes + 255) & ~(size_t)255;
        return p;
    };
    __half* hm_a        = (__half*)carve((size_t)N_NODES * D * 2);
    __half* hm_b        = (__half*)carve((size_t)N_NODES * D * 2);
    float*  hs_a        = (float*)carve((size_t)N_NODES * D * 4);
    float*  hs_b        = (float*)carve((size_t)N_NODES * D * 4);
    float*  xa1         = (float*)carve((size_t)N_NODES * D * 4);
    float*  xa2         = (float*)carve((size_t)N_NODES * D * 4);
    float*  h_final     = (float*)carve((size_t)N_NODES * D * 4);
    uint4v* rec         = (uint4v*)carve((size_t)NTILES * NT * BUCKET * 16);
    uint4v* bins        = (uint4v*)carve((size_t)NTILES * TCAP * 16);
    int*    tile_cursor = (int*)carve((size_t)NTILES * 4);
    int*    count       = (int*)carve((size_t)NTILES * NT * 4);
    __half* table       = (__half*)carve((size_t)3 * TBL_ROWS * D * 2);
    (void)ws_size; (void)in_sizes; (void)n_in; (void)out_size;

    hipMemsetAsync(tile_cursor, 0, (size_t)NTILES * 4, stream);
    hipMemsetAsync(d_out, 0, (size_t)G_GRAPHS * 4, stream);

    node_init_kernel<<<(N_NODES * 32 + 255) / 256, 256, 0, stream>>>(
        x, W_elem, W0, b0, Wmsg + 0 * D * D, Wself + 0 * D * D, Wattr, bconv,
        hm_a, hs_a, xa1, xa2);
    scatter_kernel<<<NBLK1, 256, 0, stream>>>(eidx, pos, period, wsh, tile_cursor, bins);
    table_kernel<<<(3 * TBL_ROWS + 127) / 128, 128, 0, stream>>>(Wr1, br1, Wr2, table);
    shuffle_kernel<<<NTILES, 256, 0, stream>>>(bins, tile_cursor, rec, count);

    int cgrid = (N_NODES * 64 + 255) / 256;
    conv_kernel<0, true><<<cgrid, 256, 0, stream>>>(
        hm_a, hs_a, rec, count, table, Wmsg + 1 * D * D, Wself + 1 * D * D, xa1,
        hm_b, hs_b, nullptr);
    conv_kernel<1, true><<<cgrid, 256, 0, stream>>>(
        hm_b, hs_b, rec, count, table, Wmsg + 2 * D * D, Wself + 2 * D * D, xa2,
        hm_a, hs_a, nullptr);
    conv_kernel<2, false><<<cgrid, 256, 0, stream>>>(
        hm_a, hs_a, rec, count, table, nullptr, nullptr, nullptr,
        nullptr, nullptr, h_final);

    readout_kernel<<<(N_NODES + 255) / 256, 256, 0, stream>>>(h_final, batch, Wp1, bp1, Wp2, bp2,
                                                              (float*)d_out);
}